// Round 19
// baseline (89.466 us; speedup 1.0000x reference)
//
#include <hip/hip_runtime.h>

#define IN_CH 96
#define OUT_CH 384
#define THREADS 384
#define TILE 32    // rows staged per block-iteration (12 KB LDS)

typedef float f32x4 __attribute__((ext_vector_type(4)));
typedef float f32x2 __attribute__((ext_vector_type(2)));

// R19 = R13 champion (85.1us) with ONE knob: grid 1024 -> 2048.
// 8192 tiles / 2048 blocks = exactly 4 tiles/block (uniform); 5 resident
// blocks/CU = 30/32 waves (+25% vs R13's 24). Tests whether the nt-store
// stream needs more independent wave contexts to saturate the write path
// (fills sustain 11.2 B/cy/CU write-only; we're at 7.7+reads). R7's earlier
// "more blocks hurt" was the direct-load L1-bound regime — not applicable.
// All proven pieces unchanged: LDS-staged x (L1 decongestion, +26%), nt
// stores (2x), pinned 26-float stash (+7%), ds_read_b128 broadcasts,
// 2 barriers/tile (R17/R18 proved barrier count is not the residual).
__global__ __launch_bounds__(THREADS, 5) void skel_linear_kernel(
    const float* __restrict__ x,
    const float* __restrict__ weight,
    const float* __restrict__ mask,
    const float* __restrict__ bias,
    float* __restrict__ out,
    int batch)
{
    const int t     = threadIdx.x;
    const int p     = t % 192;         // channel-pair index 0..191
    const int rl    = t / 192;         // 0..1 (uniform per wave)
    const int chan  = p * 2;
    const int joint = p >> 3;
    const int jc    = (joint - 1 < 0) ? 0 : ((joint - 1 > 21) ? 21 : joint - 1);
    const int c0    = jc * 4;          // contiguous 12-col window [c0, c0+12)

    // Masked weights + bias (26 floats: proven register-resident at this size).
    float w[2][12];
    float b[2];
#pragma unroll
    for (int j = 0; j < 2; ++j) {
        const size_t row = (size_t)(chan + j) * IN_CH;
#pragma unroll
        for (int c = 0; c < 12; ++c)
            w[j][c] = weight[row + c0 + c] * mask[row + c0 + c];
        b[j] = bias[chan + j];
    }
#pragma unroll
    for (int j = 0; j < 2; ++j) {
#pragma unroll
        for (int c = 0; c < 12; ++c)
            asm volatile("" : "+v"(w[j][c]));
        asm volatile("" : "+v"(b[j]));
    }

    __shared__ float xs[TILE * IN_CH];   // 32*96*4 = 12 KB

    const int ntiles = batch / TILE;     // 8192
    for (int tile = blockIdx.x; tile < ntiles; tile += gridDim.x) {
        // Stage 32 rows: 768 dwordx4, 2 per thread, perfectly coalesced.
        const f32x4* src = reinterpret_cast<const f32x4*>(
            x + (size_t)tile * (TILE * IN_CH));
        __syncthreads();                 // previous tile's readers done
        *reinterpret_cast<f32x4*>(&xs[4 * t])             = src[t];
        *reinterpret_cast<f32x4*>(&xs[4 * (t + THREADS)]) = src[t + THREADS];
        __syncthreads();                 // tile staged

        float* outb = out + (size_t)tile * (TILE * OUT_CH) + chan;
#pragma unroll 4
        for (int k = 0; k < TILE / 2; ++k) {
            const int rloc = 2 * k + rl;
            const float* xr = &xs[rloc * IN_CH + c0];
            const f32x4 xa = *reinterpret_cast<const f32x4*>(xr);
            const f32x4 xb = *reinterpret_cast<const f32x4*>(xr + 4);
            const f32x4 xc = *reinterpret_cast<const f32x4*>(xr + 8);

            f32x2 o2;
#pragma unroll
            for (int j = 0; j < 2; ++j) {
                float acc = b[j];
                acc = fmaf(w[j][0],  xa.x, acc);
                acc = fmaf(w[j][1],  xa.y, acc);
                acc = fmaf(w[j][2],  xa.z, acc);
                acc = fmaf(w[j][3],  xa.w, acc);
                acc = fmaf(w[j][4],  xb.x, acc);
                acc = fmaf(w[j][5],  xb.y, acc);
                acc = fmaf(w[j][6],  xb.z, acc);
                acc = fmaf(w[j][7],  xb.w, acc);
                acc = fmaf(w[j][8],  xc.x, acc);
                acc = fmaf(w[j][9],  xc.y, acc);
                acc = fmaf(w[j][10], xc.z, acc);
                acc = fmaf(w[j][11], xc.w, acc);
                o2[j] = acc;
            }

            __builtin_nontemporal_store(o2,
                reinterpret_cast<f32x2*>(outb + (size_t)rloc * OUT_CH));
        }
    }
}

extern "C" void kernel_launch(void* const* d_in, const int* in_sizes, int n_in,
                              void* d_out, int out_size, void* d_ws, size_t ws_size,
                              hipStream_t stream) {
    const float* x      = (const float*)d_in[0];
    const float* weight = (const float*)d_in[1];
    const float* mask   = (const float*)d_in[2];
    const float* bias   = (const float*)d_in[3];
    float* out          = (float*)d_out;

    const int batch = in_sizes[0] / IN_CH;   // 262144
    // 8192 tiles / 2048 blocks = exactly 4 tiles/block; 5 resident
    // blocks/CU = 30/32 waves, 60 KB LDS/CU.
    const int grid = 2048;

    skel_linear_kernel<<<grid, THREADS, 0, stream>>>(x, weight, mask, bias, out, batch);
}